// Round 13
// baseline (299.871 us; speedup 1.0000x reference)
//
#include <hip/hip_runtime.h>
#include <hip/hip_cooperative_groups.h>

namespace cg = cooperative_groups;

// FEM stiffness matvec KU = sum_e scatter(K_type(e) @ gather(U, e)).
//
// Round 13: ONE cooperative persistent kernel (pack -> bin -> accumulate)
// with two grid.sync()s. Rationale: R12 fit shows the non-K1 residue
// (~140 us) is ~60-70 us K2 + ~50-70 us launch/graph overhead, both immune
// to record-format tweaks; fusing removes 2 kernel boundaries and pays
// launch overhead once. grid.sync() supplies the device-scope fence that
// makes cross-XCD record stores visible (same as a kernel boundary did).
// Phase 1 = verified R11 structure (71.6 us): fp32 LDS filters stride 580
// read as ds_read_b128, EPT=2 with all 16 Ub gathers issued early,
// bf16-packed U, 2048-node buckets, block-aggregated tail reservation,
// 8 B bf16 records. Phase 2 aliases its 24 KB LDS accumulator onto the
// filter region (after barrier), 489 buckets / 245 blocks = 2 iters.
// Grid 245 x 1024 @ 152.5 KB LDS -> 1 block/CU, co-resident. (1024,1)
// launch bounds; R10 lesson: never starve VGPRs (spill disaster).

#define NTYPES    64
#define KSTRIDE   580            // fp32 words per type: 2320 B, 16 B-aligned
#define RSHIFT    11
#define RNODES    2048
#define MAXB      512
#define CAP       10240          // mean 8180/bucket, huge slack
#define TPB       1024
#define EPT       2
#define CHUNK     (TPB * EPT)

typedef int          nint4  __attribute__((ext_vector_type(4)));
typedef unsigned int nuint2 __attribute__((ext_vector_type(2)));

__device__ __forceinline__ unsigned bf16_rne(float f) {
    unsigned b = __float_as_uint(f);
    return (b + 0x7FFFu + ((b >> 16) & 1u)) >> 16;
}

__global__ __launch_bounds__(TPB, 1) void feconv_fused_kernel(
    const float* __restrict__ U,        // [N, 3]
    const float* __restrict__ K,        // [64, 24, 24]
    const int*   __restrict__ types,    // [E]
    const int*   __restrict__ nodIdx,   // [E, 8]
    float*       __restrict__ KU,       // [N, 3] output
    unsigned*    __restrict__ tails,    // [n_buckets]
    nuint2*      __restrict__ Ub,       // [N] packed bf16 x,y,z
    nuint2*      __restrict__ recs,     // [n_buckets * CAP]
    int n_elems, int n_nodes, int n_buckets, int n_chunks)
{
    extern __shared__ float sK[];       // 148,480 B; phase 2 aliases sAcc here
    __shared__ unsigned sCnt[MAXB];
    __shared__ unsigned sBase[MAXB];

    cg::grid_group grid = cg::this_grid();
    const int tid      = threadIdx.x;
    const int nthreads = gridDim.x * TPB;
    const int gtid     = blockIdx.x * TPB + tid;

    // ---- phase 0: pack U -> bf16, zero KU and tails; stage filters -------
    for (int n = gtid; n < n_nodes; n += nthreads) {
        const float* up = U + (size_t)n * 3;
        unsigned bx = bf16_rne(up[0]);
        unsigned by = bf16_rne(up[1]);
        unsigned bz = bf16_rne(up[2]);
        nuint2 v = { bx | (by << 16), bz };
        Ub[n] = v;
        KU[3 * n + 0] = 0.f;
        KU[3 * n + 1] = 0.f;
        KU[3 * n + 2] = 0.f;
    }
    for (int b = gtid; b < n_buckets; b += nthreads) tails[b] = 0;
    for (int w = tid; w < NTYPES * 576; w += TPB) {   // per-block LDS: no
        int t = w / 576;                               // cross-block dep
        int r = w - t * 576;
        sK[t * KSTRIDE + r] = K[w];
    }

    grid.sync();

    // ---- phase 1: compute + bin (R11 structure) --------------------------
    for (int c = blockIdx.x; c < n_chunks; c += gridDim.x) {
        __syncthreads();                 // protect sCnt reuse across iters
        for (int i = tid; i < n_buckets; i += TPB) sCnt[i] = 0;
        __syncthreads();

        const int e0 = c * CHUNK + tid;
        int     nodes[EPT][8];
        int     tt[EPT];
        nuint2  uu[EPT][8];              // in-flight packed gathers

        // pass A: connectivity + EARLY gather issue + bucket counting
#pragma unroll
        for (int k = 0; k < EPT; ++k) {
            int e = e0 + k * TPB;
            tt[k] = -1;
            if (e < n_elems) {
                tt[k] = __builtin_nontemporal_load(&types[e]);
                const nint4* q = (const nint4*)(nodIdx + (size_t)e * 8);
                nint4 a = __builtin_nontemporal_load(q);
                nint4 b = __builtin_nontemporal_load(q + 1);
                nodes[k][0] = a.x; nodes[k][1] = a.y; nodes[k][2] = a.z; nodes[k][3] = a.w;
                nodes[k][4] = b.x; nodes[k][5] = b.y; nodes[k][6] = b.z; nodes[k][7] = b.w;
#pragma unroll
                for (int j = 0; j < 8; ++j)
                    uu[k][j] = Ub[nodes[k][j]];      // issue all 16 gathers now
#pragma unroll
                for (int j = 0; j < 8; ++j)
                    atomicAdd(&sCnt[(unsigned)nodes[k][j] >> RSHIFT], 1u);
            }
        }
        __syncthreads();

        // pass B: one global tail reservation per (block, bucket)
        for (int b = tid; b < n_buckets; b += TPB) {
            unsigned cc = sCnt[b];
            sBase[b] = cc ? atomicAdd(&tails[b], cc) : 0u;
            sCnt[b] = 0;                 // reuse as local cursor
        }
        __syncthreads();

        // pass C: unpack, matvec via ds_read_b128 filters, 8 B records
#pragma unroll
        for (int k = 0; k < EPT; ++k) {
            if (tt[k] < 0) continue;

            float ue[24];
#pragma unroll
            for (int j = 0; j < 8; ++j) {
                nuint2 v = uu[k][j];
                ue[3 * j + 0] = __uint_as_float(v.x << 16);
                ue[3 * j + 1] = __uint_as_float(v.x & 0xFFFF0000u);
                ue[3 * j + 2] = __uint_as_float(v.y << 16);
            }

            const float4* Kt4 = (const float4*)(sK + tt[k] * KSTRIDE);
#pragma unroll
            for (int j = 0; j < 8; ++j) {
                float a0 = 0.f, a1 = 0.f, a2 = 0.f;
#pragma unroll
                for (int q = 0; q < 6; ++q) {
                    float4 k0 = Kt4[(3 * j + 0) * 6 + q];
                    float4 k1 = Kt4[(3 * j + 1) * 6 + q];
                    float4 k2 = Kt4[(3 * j + 2) * 6 + q];
                    float u0 = ue[4 * q + 0], u1 = ue[4 * q + 1];
                    float u2 = ue[4 * q + 2], u3 = ue[4 * q + 3];
                    a0 += k0.x * u0 + k0.y * u1 + k0.z * u2 + k0.w * u3;
                    a1 += k1.x * u0 + k1.y * u1 + k1.z * u2 + k1.w * u3;
                    a2 += k2.x * u0 + k2.y * u1 + k2.z * u2 + k2.w * u3;
                }
                unsigned n = (unsigned)nodes[k][j];
                unsigned b = n >> RSHIFT;
                unsigned pos = sBase[b] + atomicAdd(&sCnt[b], 1u);
                if (pos < CAP) {
                    unsigned local = n & (RNODES - 1);
                    nuint2 r = { bf16_rne(a0) | (bf16_rne(a1) << 16),
                                 bf16_rne(a2) | (local << 16) };
                    recs[(size_t)b * CAP + pos] = r;
                } else {  // statistically unreachable; absolute correctness
                    atomicAdd(&KU[(size_t)n * 3 + 0], a0);
                    atomicAdd(&KU[(size_t)n * 3 + 1], a1);
                    atomicAdd(&KU[(size_t)n * 3 + 2], a2);
                }
            }
        }
    }

    grid.sync();

    // ---- phase 2: accumulate per bucket (sAcc aliases sK) ----------------
    float* sAcc = sK;                    // 24 KB of the 148 KB region
    for (int b = blockIdx.x; b < n_buckets; b += gridDim.x) {
        __syncthreads();
        for (int i = tid; i < RNODES * 3; i += TPB) sAcc[i] = 0.f;
        __syncthreads();

        unsigned cnt = tails[b];
        if (cnt > CAP) cnt = CAP;
        const nuint2* base = recs + (size_t)b * CAP;
        for (unsigned i = tid; i < cnt; i += TPB) {
            nuint2 r = base[i];
            unsigned o = (r.y >> 16) * 3;
            atomicAdd(&sAcc[o + 0], __uint_as_float(r.x << 16));         // ds_add_f32
            atomicAdd(&sAcc[o + 1], __uint_as_float(r.x & 0xFFFF0000u));
            atomicAdd(&sAcc[o + 2], __uint_as_float(r.y << 16));
        }
        __syncthreads();

        const int nbase = b * RNODES;
        int limit = n_nodes - nbase;
        if (limit > RNODES) limit = RNODES;
        limit *= 3;
        float* out = KU + (size_t)nbase * 3;
        for (int i = tid; i < limit; i += TPB) out[i] += sAcc[i];
    }
}

// ---- fallback (round-0 style) --------------------------------------------

__global__ __launch_bounds__(256) void feconv_elem_kernel(
    const float* __restrict__ U, const float* __restrict__ K,
    const int* __restrict__ types, const int* __restrict__ nodIdx,
    float* __restrict__ KU, int n_elems)
{
    int e = blockIdx.x * blockDim.x + threadIdx.x;
    if (e >= n_elems) return;
    int t = types[e];
    const int4* idx4 = (const int4*)(nodIdx + (size_t)e * 8);
    int4 iA = idx4[0], iB = idx4[1];
    int nodes[8] = {iA.x, iA.y, iA.z, iA.w, iB.x, iB.y, iB.z, iB.w};
    float ue[24];
#pragma unroll
    for (int j = 0; j < 8; ++j) {
        const float* up = U + (size_t)nodes[j] * 3;
        ue[3 * j + 0] = up[0]; ue[3 * j + 1] = up[1]; ue[3 * j + 2] = up[2];
    }
    const float* Kt = K + (size_t)t * 576;
#pragma unroll
    for (int i = 0; i < 24; ++i) {
        const float4* row = (const float4*)(Kt + i * 24);
        float acc = 0.f;
#pragma unroll
        for (int q = 0; q < 6; ++q) {
            float4 k = row[q];
            acc += k.x * ue[4 * q + 0] + k.y * ue[4 * q + 1]
                 + k.z * ue[4 * q + 2] + k.w * ue[4 * q + 3];
        }
        atomicAdd(&KU[(size_t)nodes[i / 3] * 3 + (i % 3)], acc);
    }
}

extern "C" void kernel_launch(void* const* d_in, const int* in_sizes, int n_in,
                              void* d_out, int out_size, void* d_ws, size_t ws_size,
                              hipStream_t stream) {
    const float* U      = (const float*)d_in[0];
    const float* Kf     = (const float*)d_in[1];
    const int*   types  = (const int*)d_in[2];
    const int*   nodIdx = (const int*)d_in[3];
    float*       KU     = (float*)d_out;

    int n_elems  = in_sizes[2];
    int n_nodes  = in_sizes[0] / 3;
    int n_buckets = (n_nodes + RNODES - 1) / RNODES;   // 489 for N=1M
    int n_chunks  = (n_elems + CHUNK - 1) / CHUNK;     // 245 for E=500K

    // ws layout: [0, 4096) tails | [4096, +8B*n_nodes) Ub | then recs
    const size_t ub_off  = 4096;
    const size_t rec_off = ub_off + (((size_t)n_nodes * 8 + 255) & ~255ull);
    const size_t need    = rec_off + (size_t)n_buckets * CAP * 8;

    if (n_buckets <= MAXB && ws_size >= need) {
        unsigned* tails = (unsigned*)d_ws;
        nuint2*   Ub    = (nuint2*)((char*)d_ws + ub_off);
        nuint2*   recs  = (nuint2*)((char*)d_ws + rec_off);

        size_t lds_bytes = (size_t)NTYPES * KSTRIDE * sizeof(float);  // 148,480
        int grid = n_chunks < 256 ? n_chunks : 256;   // 1 block/CU co-resident

        void* args[] = { (void*)&U, (void*)&Kf, (void*)&types, (void*)&nodIdx,
                         (void*)&KU, (void*)&tails, (void*)&Ub, (void*)&recs,
                         (void*)&n_elems, (void*)&n_nodes, (void*)&n_buckets,
                         (void*)&n_chunks };
        (void)hipLaunchCooperativeKernel((void*)feconv_fused_kernel,
                                         dim3(grid), dim3(TPB),
                                         args, (unsigned)lds_bytes, stream);
    } else {
        (void)hipMemsetAsync(KU, 0, (size_t)out_size * sizeof(float), stream);
        int block = 256;
        int grid = (n_elems + block - 1) / block;
        feconv_elem_kernel<<<grid, block, 0, stream>>>(
            U, Kf, types, nodIdx, KU, n_elems);
    }
}

// Round 14
// 214.623 us; speedup vs baseline: 1.3972x; 1.3972x over previous
//
#include <hip/hip_runtime.h>

// FEM stiffness matvec KU = sum_e scatter(K_type(e) @ gather(U, e)).
//
// Round 14 = R11 (best: 216.4 us; K1 71.6 us) + surgical deltas:
//  - pack kernel also zeroes KU + tails (removes 2 memset dispatches).
//  - 8 B bf16 records (K2 stream 48->32 MB); KEEP RNODES 2048 / MAXB 512
//    (R12's 1024/1024 cost K1 +5 us via counter-loop + line raggedness).
//  - K2: TPB 256 (24 KB LDS -> ~6 blocks/CU latency hiding, vs 2) and
//    paired 16 B record loads (halve load-issue count).
// R13 lesson: the ~80 us bench-vs-kernel gap is harness/graph overhead,
// NOT per-launch cost — fusion into one cooperative kernel regressed.
// K1 carries (verified R11): fp32 LDS filters stride 580 via ds_read_b128,
// EPT=2 with all 16 Ub gathers issued in pass A, bf16-packed U,
// block-aggregated tail reservation, launch_bounds (1024,4) (R10: VGPR
// starvation => scratch-spill disaster).

#define NTYPES    64
#define KSTRIDE   580            // fp32 words per type: 2320 B, 16 B-aligned
#define RSHIFT    11
#define RNODES    2048
#define MAXB      512
#define CAP       10240          // mean 8180/bucket, huge slack (even: 16 B pairs)
#define K1_TPB    1024
#define K1_EPT    2
#define K1_CHUNK  (K1_TPB * K1_EPT)
#define K2_TPB    256
#define PREP_TPB  256

typedef int          nint4  __attribute__((ext_vector_type(4)));
typedef unsigned int nuint2 __attribute__((ext_vector_type(2)));
typedef unsigned int nuint4 __attribute__((ext_vector_type(4)));

__device__ __forceinline__ unsigned bf16_rne(float f) {
    unsigned b = __float_as_uint(f);
    return (b + 0x7FFFu + ((b >> 16) & 1u)) >> 16;
}

// ---- phase 0: pack U -> bf16 triples; zero KU and tails -------------------

__global__ __launch_bounds__(PREP_TPB) void pack_u_kernel(
    const float* __restrict__ U, nuint2* __restrict__ Ub,
    float* __restrict__ KU, unsigned* __restrict__ tails,
    int n_nodes, int n_buckets)
{
    int n = blockIdx.x * PREP_TPB + threadIdx.x;
    if (n < n_buckets) tails[n] = 0;
    if (n >= n_nodes) return;
    const float* up = U + (size_t)n * 3;
    unsigned bx = bf16_rne(up[0]);
    unsigned by = bf16_rne(up[1]);
    unsigned bz = bf16_rne(up[2]);
    nuint2 v = { bx | (by << 16), bz };
    Ub[n] = v;
    KU[3 * n + 0] = 0.f;
    KU[3 * n + 1] = 0.f;
    KU[3 * n + 2] = 0.f;
}

// ---- phase 1: compute + bin ----------------------------------------------

__global__ __launch_bounds__(K1_TPB, 4) void feconv_bin_kernel(
    const nuint2* __restrict__ Ub,      // [N] packed bf16 x,y,z
    const float* __restrict__ K,        // [64, 24, 24]
    const int*   __restrict__ types,    // [E]
    const int*   __restrict__ nodIdx,   // [E, 8]
    float*       __restrict__ KU,       // overflow fallback only
    unsigned*    __restrict__ tails,    // [n_buckets]
    nuint2*      __restrict__ recs,     // [n_buckets * CAP]
    int n_elems, int n_buckets)
{
    extern __shared__ float sK[];       // [64 * KSTRIDE] words, per-type rows
    __shared__ unsigned sCnt[MAXB];
    __shared__ unsigned sBase[MAXB];

    for (int w = threadIdx.x; w < NTYPES * 576; w += K1_TPB) {
        int t = w / 576;
        int r = w - t * 576;
        sK[t * KSTRIDE + r] = K[w];
    }
    for (int i = threadIdx.x; i < n_buckets; i += K1_TPB) sCnt[i] = 0;
    __syncthreads();

    const int e0 = blockIdx.x * K1_CHUNK + threadIdx.x;
    int     nodes[K1_EPT][8];
    int     tt[K1_EPT];
    nuint2  uu[K1_EPT][8];              // in-flight packed gathers

    // pass A: connectivity + EARLY gather issue + bucket counting
#pragma unroll
    for (int k = 0; k < K1_EPT; ++k) {
        int e = e0 + k * K1_TPB;
        tt[k] = -1;
        if (e < n_elems) {
            tt[k] = __builtin_nontemporal_load(&types[e]);
            const nint4* q = (const nint4*)(nodIdx + (size_t)e * 8);
            nint4 a = __builtin_nontemporal_load(q);
            nint4 b = __builtin_nontemporal_load(q + 1);
            nodes[k][0] = a.x; nodes[k][1] = a.y; nodes[k][2] = a.z; nodes[k][3] = a.w;
            nodes[k][4] = b.x; nodes[k][5] = b.y; nodes[k][6] = b.z; nodes[k][7] = b.w;
#pragma unroll
            for (int j = 0; j < 8; ++j)
                uu[k][j] = Ub[nodes[k][j]];          // issue all 16 gathers now
#pragma unroll
            for (int j = 0; j < 8; ++j)
                atomicAdd(&sCnt[(unsigned)nodes[k][j] >> RSHIFT], 1u);
        }
    }
    __syncthreads();

    // pass B: one global tail reservation per (block, bucket)
    for (int b = threadIdx.x; b < n_buckets; b += K1_TPB) {
        unsigned c = sCnt[b];
        sBase[b] = c ? atomicAdd(&tails[b], c) : 0u;
        sCnt[b] = 0;                     // reuse as local cursor
    }
    __syncthreads();

    // pass C: unpack, matvec via ds_read_b128 filters, write 8 B records
#pragma unroll
    for (int k = 0; k < K1_EPT; ++k) {
        if (tt[k] < 0) continue;

        float ue[24];
#pragma unroll
        for (int j = 0; j < 8; ++j) {
            nuint2 v = uu[k][j];
            ue[3 * j + 0] = __uint_as_float(v.x << 16);
            ue[3 * j + 1] = __uint_as_float(v.x & 0xFFFF0000u);
            ue[3 * j + 2] = __uint_as_float(v.y << 16);
        }

        const float4* Kt4 = (const float4*)(sK + tt[k] * KSTRIDE);
#pragma unroll
        for (int j = 0; j < 8; ++j) {
            float a0 = 0.f, a1 = 0.f, a2 = 0.f;
#pragma unroll
            for (int q = 0; q < 6; ++q) {
                float4 k0 = Kt4[(3 * j + 0) * 6 + q];
                float4 k1 = Kt4[(3 * j + 1) * 6 + q];
                float4 k2 = Kt4[(3 * j + 2) * 6 + q];
                float u0 = ue[4 * q + 0], u1 = ue[4 * q + 1];
                float u2 = ue[4 * q + 2], u3 = ue[4 * q + 3];
                a0 += k0.x * u0 + k0.y * u1 + k0.z * u2 + k0.w * u3;
                a1 += k1.x * u0 + k1.y * u1 + k1.z * u2 + k1.w * u3;
                a2 += k2.x * u0 + k2.y * u1 + k2.z * u2 + k2.w * u3;
            }
            unsigned n = (unsigned)nodes[k][j];
            unsigned b = n >> RSHIFT;
            unsigned pos = sBase[b] + atomicAdd(&sCnt[b], 1u);
            if (pos < CAP) {
                unsigned local = n & (RNODES - 1);
                nuint2 r = { bf16_rne(a0) | (bf16_rne(a1) << 16),
                             bf16_rne(a2) | (local << 16) };
                recs[(size_t)b * CAP + pos] = r;
            } else {  // statistically unreachable; absolute correctness
                atomicAdd(&KU[(size_t)n * 3 + 0], a0);
                atomicAdd(&KU[(size_t)n * 3 + 1], a1);
                atomicAdd(&KU[(size_t)n * 3 + 2], a2);
            }
        }
    }
}

// ---- phase 2: accumulate per bucket --------------------------------------

__global__ __launch_bounds__(K2_TPB) void feconv_acc_kernel(
    const nuint2*   __restrict__ recs,
    const unsigned* __restrict__ tails,
    float*          __restrict__ KU,     // [N, 3], pre-zeroed
    int n_nodes)
{
    __shared__ float sAcc[RNODES * 3];   // 24 KB -> ~6 blocks/CU
    const int b = blockIdx.x;

    for (int i = threadIdx.x; i < RNODES * 3; i += K2_TPB) sAcc[i] = 0.f;
    __syncthreads();

    unsigned cnt = tails[b];
    if (cnt > CAP) cnt = CAP;
    const nuint2* base = recs + (size_t)b * CAP;
    const nuint4* base4 = (const nuint4*)base;       // 16 B-aligned (CAP even)

    unsigned npairs = cnt >> 1;
    for (unsigned i = threadIdx.x; i < npairs; i += K2_TPB) {
        nuint4 p = base4[i];                          // two records, one load
        unsigned o0 = (p.y >> 16) * 3;
        atomicAdd(&sAcc[o0 + 0], __uint_as_float(p.x << 16));
        atomicAdd(&sAcc[o0 + 1], __uint_as_float(p.x & 0xFFFF0000u));
        atomicAdd(&sAcc[o0 + 2], __uint_as_float(p.y << 16));
        unsigned o1 = (p.w >> 16) * 3;
        atomicAdd(&sAcc[o1 + 0], __uint_as_float(p.z << 16));
        atomicAdd(&sAcc[o1 + 1], __uint_as_float(p.z & 0xFFFF0000u));
        atomicAdd(&sAcc[o1 + 2], __uint_as_float(p.w << 16));
    }
    if ((cnt & 1u) && threadIdx.x == 0) {             // odd tail record
        nuint2 r = base[cnt - 1];
        unsigned o = (r.y >> 16) * 3;
        atomicAdd(&sAcc[o + 0], __uint_as_float(r.x << 16));
        atomicAdd(&sAcc[o + 1], __uint_as_float(r.x & 0xFFFF0000u));
        atomicAdd(&sAcc[o + 2], __uint_as_float(r.y << 16));
    }
    __syncthreads();

    const int nbase = b * RNODES;
    int limit = n_nodes - nbase;
    if (limit > RNODES) limit = RNODES;
    limit *= 3;
    float* out = KU + (size_t)nbase * 3;
    for (int i = threadIdx.x; i < limit; i += K2_TPB) out[i] += sAcc[i];
}

// ---- fallback (round-0 style) --------------------------------------------

__global__ __launch_bounds__(256) void feconv_elem_kernel(
    const float* __restrict__ U, const float* __restrict__ K,
    const int* __restrict__ types, const int* __restrict__ nodIdx,
    float* __restrict__ KU, int n_elems)
{
    int e = blockIdx.x * blockDim.x + threadIdx.x;
    if (e >= n_elems) return;
    int t = types[e];
    const int4* idx4 = (const int4*)(nodIdx + (size_t)e * 8);
    int4 iA = idx4[0], iB = idx4[1];
    int nodes[8] = {iA.x, iA.y, iA.z, iA.w, iB.x, iB.y, iB.z, iB.w};
    float ue[24];
#pragma unroll
    for (int j = 0; j < 8; ++j) {
        const float* up = U + (size_t)nodes[j] * 3;
        ue[3 * j + 0] = up[0]; ue[3 * j + 1] = up[1]; ue[3 * j + 2] = up[2];
    }
    const float* Kt = K + (size_t)t * 576;
#pragma unroll
    for (int i = 0; i < 24; ++i) {
        const float4* row = (const float4*)(Kt + i * 24);
        float acc = 0.f;
#pragma unroll
        for (int q = 0; q < 6; ++q) {
            float4 k = row[q];
            acc += k.x * ue[4 * q + 0] + k.y * ue[4 * q + 1]
                 + k.z * ue[4 * q + 2] + k.w * ue[4 * q + 3];
        }
        atomicAdd(&KU[(size_t)nodes[i / 3] * 3 + (i % 3)], acc);
    }
}

extern "C" void kernel_launch(void* const* d_in, const int* in_sizes, int n_in,
                              void* d_out, int out_size, void* d_ws, size_t ws_size,
                              hipStream_t stream) {
    const float* U      = (const float*)d_in[0];
    const float* Kf     = (const float*)d_in[1];
    const int*   types  = (const int*)d_in[2];
    const int*   nodIdx = (const int*)d_in[3];
    float*       KU     = (float*)d_out;

    const int n_elems = in_sizes[2];
    const int n_nodes = in_sizes[0] / 3;
    const int n_buckets = (n_nodes + RNODES - 1) / RNODES;   // 489 for N=1M

    // ws layout: [0, 4096) tails | [4096, +8B*n_nodes) Ub | then recs
    const size_t ub_off  = 4096;
    const size_t rec_off = ub_off + (((size_t)n_nodes * 8 + 255) & ~255ull);
    const size_t need    = rec_off + (size_t)n_buckets * CAP * 8;

    if (n_buckets <= MAXB && ws_size >= need) {
        unsigned* tails = (unsigned*)d_ws;
        nuint2*   Ub    = (nuint2*)((char*)d_ws + ub_off);
        nuint2*   recs  = (nuint2*)((char*)d_ws + rec_off);

        int gridP = (n_nodes + PREP_TPB - 1) / PREP_TPB;
        pack_u_kernel<<<gridP, PREP_TPB, 0, stream>>>(
            U, Ub, KU, tails, n_nodes, n_buckets);

        size_t lds_bytes = (size_t)NTYPES * KSTRIDE * sizeof(float);  // 148,480
        int grid1 = (n_elems + K1_CHUNK - 1) / K1_CHUNK;               // 245
        feconv_bin_kernel<<<grid1, K1_TPB, lds_bytes, stream>>>(
            Ub, Kf, types, nodIdx, KU, tails, recs, n_elems, n_buckets);
        feconv_acc_kernel<<<n_buckets, K2_TPB, 0, stream>>>(
            recs, tails, KU, n_nodes);
    } else {
        (void)hipMemsetAsync(KU, 0, (size_t)out_size * sizeof(float), stream);
        int block = 256;
        int grid = (n_elems + block - 1) / block;
        feconv_elem_kernel<<<grid, block, 0, stream>>>(
            U, Kf, types, nodIdx, KU, n_elems);
    }
}